// Round 1
// baseline (1951.587 us; speedup 1.0000x reference)
//
#include <hip/hip_runtime.h>
#include <math.h>

// PaiNN energy + analytic coord-gradient, f32 correctness-first implementation.
// Needs ~260 MB of d_ws scratch.

#define NA 8192
#define NE 131072
#define FD 128
#define FD3 384
#define NBASE 20
#define HD 64
#define RCUT 5.0f
#define PIF 3.14159265358979f

static __device__ __forceinline__ float silu_f(float x) {
    return x / (1.f + expf(-x));
}
static __device__ __forceinline__ float dsilu_f(float x) {
    float s = 1.f / (1.f + expf(-x));
    return s * (1.f + x * (1.f - s));
}

// ---------------- generic tiled f32 GEMM: C = [silu?](A) @ W (+bias) (*dsilu(pre)) (+addbuf) ----
__global__ __launch_bounds__(256) void gemm_kernel(
    const float* __restrict__ A, const float* __restrict__ W,
    const float* __restrict__ bias, const float* __restrict__ dsil,
    const float* __restrict__ addbuf, float* __restrict__ C,
    int M, int N, int K, int asilu, int acc)
{
    __shared__ float As[16][65];
    __shared__ float Ws[16][65];
    int tid = threadIdx.x;
    int tx = tid & 15, ty = tid >> 4;
    int row0 = blockIdx.y * 64, col0 = blockIdx.x * 64;
    float accv[4][4];
    #pragma unroll
    for (int i = 0; i < 4; ++i)
        #pragma unroll
        for (int j = 0; j < 4; ++j) accv[i][j] = 0.f;
    for (int k0 = 0; k0 < K; k0 += 16) {
        #pragma unroll
        for (int p = 0; p < 4; ++p) {
            int rr = (tid >> 4) + p * 16;
            int kk = tid & 15;
            float v = A[(size_t)(row0 + rr) * K + k0 + kk];
            if (asilu) v = v / (1.f + expf(-v));
            As[kk][rr] = v;
        }
        #pragma unroll
        for (int p = 0; p < 4; ++p) {
            int kk = (tid >> 6) + p * 4;
            int nn = tid & 63;
            Ws[kk][nn] = W[(size_t)(k0 + kk) * N + col0 + nn];
        }
        __syncthreads();
        #pragma unroll
        for (int kk = 0; kk < 16; ++kk) {
            float a4[4], w4[4];
            #pragma unroll
            for (int i = 0; i < 4; ++i) a4[i] = As[kk][ty * 4 + i];
            #pragma unroll
            for (int j = 0; j < 4; ++j) w4[j] = Ws[kk][tx * 4 + j];
            #pragma unroll
            for (int i = 0; i < 4; ++i)
                #pragma unroll
                for (int j = 0; j < 4; ++j)
                    accv[i][j] = fmaf(a4[i], w4[j], accv[i][j]);
        }
        __syncthreads();
    }
    #pragma unroll
    for (int i = 0; i < 4; ++i) {
        int r = row0 + ty * 4 + i;
        #pragma unroll
        for (int j = 0; j < 4; ++j) {
            int c = col0 + tx * 4 + j;
            float v = accv[i][j];
            if (bias) v += bias[c];
            size_t idx = (size_t)r * N + c;
            if (dsil) { float pz = dsil[idx]; float s = 1.f / (1.f + expf(-pz)); v *= s * (1.f + pz * (1.f - s)); }
            if (addbuf) v += addbuf[idx];
            if (acc) C[idx] += v; else C[idx] = v;
        }
    }
}

// ---------------- small helpers ----------------
__global__ void transpose_kernel(const float* in, float* out, int R, int C) {
    int i = blockIdx.x * blockDim.x + threadIdx.x;
    if (i < R * C) { int r = i / C, c = i % C; out[(size_t)c * R + r] = in[i]; }
}

__global__ void embed_kernel(const int* at_no, const float* emb, float* x) {
    int i = blockIdx.x * blockDim.x + threadIdx.x;   // NA*FD threads
    int n = i >> 7, f = i & 127;
    x[i] = emb[(size_t)at_no[n] * FD + f];
}

// ---------------- edge geometry forward ----------------
__global__ void geom_fwd_kernel(const float* coord, const int* ei,
    float* d_e, float* unit_e, float* rbf_e, float* drbf_e, float* fcut_e, float* dfc_e)
{
    int e = blockIdx.x * blockDim.x + threadIdx.x;
    if (e >= NE) return;
    int s = ei[e], t = ei[NE + e];
    float rx = coord[t * 3 + 0] - coord[s * 3 + 0];
    float ry = coord[t * 3 + 1] - coord[s * 3 + 1];
    float rz = coord[t * 3 + 2] - coord[s * 3 + 2];
    float r2 = rx * rx + ry * ry + rz * rz;
    float dd = sqrtf(r2 + 1e-12f);
    float inv = 1.f / dd;
    d_e[e] = dd;
    unit_e[e * 3 + 0] = rx * inv; unit_e[e * 3 + 1] = ry * inv; unit_e[e * 3 + 2] = rz * inv;
    const float c0 = 0.6324555320336759f;   // sqrt(2/5)
    for (int k = 0; k < NBASE; ++k) {
        float nk = (k + 1) * (PIF / RCUT);
        float sn, cs; sincosf(nk * dd, &sn, &cs);
        rbf_e[(size_t)e * NBASE + k] = c0 * sn * inv;
        drbf_e[(size_t)e * NBASE + k] = c0 * (nk * cs * inv - sn * inv * inv);
    }
    if (dd < RCUT) {
        float sn, cs; sincosf(PIF * dd / RCUT, &sn, &cs);
        fcut_e[e] = 0.5f * (cs + 1.f);
        dfc_e[e] = -0.5f * (PIF / RCUT) * sn;
    } else { fcut_e[e] = 0.f; dfc_e[e] = 0.f; }
}

// ---------------- CSR build ----------------
__global__ void hist_kernel(const int* ei, int* cnt_dst, int* cnt_src) {
    int e = blockIdx.x * blockDim.x + threadIdx.x;
    if (e >= NE) return;
    atomicAdd(&cnt_src[ei[e]], 1);
    atomicAdd(&cnt_dst[ei[NE + e]], 1);
}

__global__ __launch_bounds__(1024) void scan_kernel(
    const int* cnt_dst, const int* cnt_src,
    int* off_dst, int* off_src, int* cur_dst, int* cur_src)
{
    __shared__ int part[1024];
    const int* cnt = (blockIdx.x == 0) ? cnt_dst : cnt_src;
    int* off = (blockIdx.x == 0) ? off_dst : off_src;
    int* cur = (blockIdx.x == 0) ? cur_dst : cur_src;
    int t = threadIdx.x;
    int base = t * 8;
    int loc[8]; int s = 0;
    #pragma unroll
    for (int i = 0; i < 8; ++i) { loc[i] = s; s += cnt[base + i]; }
    part[t] = s;
    __syncthreads();
    for (int d = 1; d < 1024; d <<= 1) {
        int v = part[t];
        int w = (t >= d) ? part[t - d] : 0;
        __syncthreads();
        part[t] = v + w;
        __syncthreads();
    }
    int pre = (t == 0) ? 0 : part[t - 1];
    #pragma unroll
    for (int i = 0; i < 8; ++i) { int o = pre + loc[i]; off[base + i] = o; cur[base + i] = o; }
    if (t == 1023) off[NA] = part[1023];
}

__global__ void scatter_kernel(const int* ei, int* cur_dst, int* cur_src, int* perm_dst, int* perm_src) {
    int e = blockIdx.x * blockDim.x + threadIdx.x;
    if (e >= NE) return;
    int pd = atomicAdd(&cur_dst[ei[NE + e]], 1); perm_dst[pd] = e;
    int ps = atomicAdd(&cur_src[ei[e]], 1);      perm_src[ps] = e;
}

// ---------------- message forward (per-dst-atom aggregation) ----------------
__global__ __launch_bounds__(128) void msg_fwd_kernel(
    const int* row_off_dst, const int* perm_dst, const int* src_arr,
    const float* rbf_e, const float* fcut_e, const float* unit_e,
    const float* phi, const float* Wr, const float* br,
    const float* x_in, const float* v_in,   // v_in may be null (block 0)
    float* x_mid, float* v_mid)
{
    __shared__ float sWr[NBASE * FD3];
    __shared__ float sbr[FD3];
    int n = blockIdx.x;
    int f = threadIdx.x;
    for (int i = f; i < NBASE * FD3; i += FD) sWr[i] = Wr[i];
    for (int i = f; i < FD3; i += FD) sbr[i] = br[i];
    __syncthreads();
    float xa = 0.f, va0 = 0.f, va1 = 0.f, va2 = 0.f;
    int e0 = row_off_dst[n], e1 = row_off_dst[n + 1];
    for (int ii = e0; ii < e1; ++ii) {
        int e = perm_dst[ii];
        int s = src_arr[e];
        float fc = fcut_e[e];
        float raw0 = sbr[f], raw1 = sbr[FD + f], raw2 = sbr[2 * FD + f];
        #pragma unroll
        for (int k = 0; k < NBASE; ++k) {
            float r = rbf_e[(size_t)e * NBASE + k];
            raw0 = fmaf(r, sWr[k * FD3 + f], raw0);
            raw1 = fmaf(r, sWr[k * FD3 + FD + f], raw1);
            raw2 = fmaf(r, sWr[k * FD3 + 2 * FD + f], raw2);
        }
        float f0 = raw0 * fc, f1 = raw1 * fc, f2 = raw2 * fc;
        const float* ph = phi + (size_t)s * FD3;
        float m0 = ph[f] * f0, m1 = ph[FD + f] * f1, m2 = ph[2 * FD + f] * f2;
        xa += m0;
        float u0 = unit_e[e * 3], u1 = unit_e[e * 3 + 1], u2 = unit_e[e * 3 + 2];
        float vs0 = 0.f, vs1 = 0.f, vs2 = 0.f;
        if (v_in) {
            const float* vp = v_in + (size_t)s * 3 * FD;
            vs0 = vp[f]; vs1 = vp[FD + f]; vs2 = vp[2 * FD + f];
        }
        va0 += m1 * vs0 + m2 * u0;
        va1 += m1 * vs1 + m2 * u1;
        va2 += m1 * vs2 + m2 * u2;
    }
    size_t xb = (size_t)n * FD + f;
    x_mid[xb] = x_in[xb] + xa;
    size_t vb = (size_t)n * 3 * FD + f;
    float p0 = 0.f, p1 = 0.f, p2 = 0.f;
    if (v_in) { p0 = v_in[vb]; p1 = v_in[vb + FD]; p2 = v_in[vb + 2 * FD]; }
    v_mid[vb] = p0 + va0; v_mid[vb + FD] = p1 + va1; v_mid[vb + 2 * FD] = p2 + va2;
}

// ---------------- update-block pointwise kernels ----------------
__global__ void vnorm_cat_kernel(const float* xmid, const float* vv, float* vnorm, float* cat) {
    int i = blockIdx.x * blockDim.x + threadIdx.x;  // NA*FD
    int n = i >> 7, g = i & 127;
    size_t vb = (size_t)n * 3 * FD + g;
    float a = vv[vb], b = vv[vb + FD], c = vv[vb + 2 * FD];
    float vn = sqrtf(a * a + b * b + c * c + 1e-12f);
    vnorm[i] = vn;
    cat[(size_t)n * 2 * FD + g] = xmid[i];
    cat[(size_t)n * 2 * FD + FD + g] = vn;
}

__global__ void combine_kernel(const float* xmid, const float* vmid,
    const float* uv, const float* vv, const float* a_,
    float* x_out, float* v_out /* nullable */)
{
    int i = blockIdx.x * blockDim.x + threadIdx.x;  // NA*FD
    int n = i >> 7, g = i & 127;
    size_t vb = (size_t)n * 3 * FD + g;
    float uv0 = uv[vb], uv1 = uv[vb + FD], uv2 = uv[vb + 2 * FD];
    float vv0 = vv[vb], vv1 = vv[vb + FD], vv2 = vv[vb + 2 * FD];
    float S = uv0 * vv0 + uv1 * vv1 + uv2 * vv2;
    const float* ar = a_ + (size_t)n * FD3;
    x_out[i] = xmid[i] + ar[FD + g] * S + ar[2 * FD + g];
    if (v_out) {
        float avv = ar[g];
        v_out[vb] = vmid[vb] + avv * uv0;
        v_out[vb + FD] = vmid[vb + FD] + avv * uv1;
        v_out[vb + 2 * FD] = vmid[vb + 2 * FD] + avv * uv2;
    }
}

// ---------------- output head ----------------
__global__ __launch_bounds__(256) void energy_kernel(
    const float* tout, const float* ow2, const float* ob2,
    const float* atom_sp, const int* at_no, float* out)
{
    int n = blockIdx.x * 256 + threadIdx.x;   // NA exact
    float e = ob2[0] + atom_sp[at_no[n]];
    for (int h = 0; h < HD; ++h) {
        float t = tout[(size_t)n * HD + h];
        e = fmaf(silu_f(t), ow2[h], e);
    }
    #pragma unroll
    for (int off = 32; off > 0; off >>= 1) e += __shfl_down(e, off);
    __shared__ float s[4];
    int lane = threadIdx.x & 63, wv = threadIdx.x >> 6;
    if (lane == 0) s[wv] = e;
    __syncthreads();
    if (threadIdx.x == 0) atomicAdd(out, s[0] + s[1] + s[2] + s[3]);
}

__global__ __launch_bounds__(128) void head_bwd_kernel(
    const float* tout, const float* ow1, const float* ow2, float* gx)
{
    __shared__ float sh[HD];
    int n = blockIdx.x, f = threadIdx.x;
    if (f < HD) {
        float p = tout[(size_t)n * HD + f];
        sh[f] = dsilu_f(p) * ow2[f];
    }
    __syncthreads();
    float g = 0.f;
    #pragma unroll
    for (int h = 0; h < HD; ++h) g = fmaf(sh[h], ow1[f * HD + h], g);
    gx[(size_t)n * FD + f] = g;
}

// ---------------- update-block backward pointwise ----------------
__global__ void ubwd1_kernel(const float* gx, const float* gv,
    const float* uv, const float* vv, float* g_a)
{
    int i = blockIdx.x * blockDim.x + threadIdx.x;  // NA*FD
    int n = i >> 7, g = i & 127;
    size_t vb = (size_t)n * 3 * FD + g;
    float uv0 = uv[vb], uv1 = uv[vb + FD], uv2 = uv[vb + 2 * FD];
    float vv0 = vv[vb], vv1 = vv[vb + FD], vv2 = vv[vb + 2 * FD];
    float gv0 = gv[vb], gv1 = gv[vb + FD], gv2 = gv[vb + 2 * FD];
    float gxv = gx[i];
    float S = uv0 * vv0 + uv1 * vv1 + uv2 * vv2;
    size_t ab = (size_t)n * FD3;
    g_a[ab + g]           = gv0 * uv0 + gv1 * uv1 + gv2 * uv2;   // g w.r.t. a_vv
    g_a[ab + FD + g]      = gxv * S;                              // g w.r.t. a_sv
    g_a[ab + 2 * FD + g]  = gxv;                                  // g w.r.t. a_ss
}

// NOTE: uv/vv are read then overwritten in place (g_uv/g_vv); no __restrict__ here on purpose.
__global__ void ubwd2_kernel(const float* gx_in, const float* gv_in,
    const float* a_, const float* vnorm, const float* g_cat,
    float* uv, float* vv, float* gx_mid, float* gv_tmp)
{
    int i = blockIdx.x * blockDim.x + threadIdx.x;  // NA*FD
    int n = i >> 7, g = i & 127;
    size_t vb = (size_t)n * 3 * FD + g, ab = (size_t)n * FD3;
    float gxv = gx_in[i];
    float gS = gxv * a_[ab + FD + g];
    float avv = a_[ab + g];
    float gvn = g_cat[(size_t)n * 2 * FD + FD + g];
    float c = gvn / vnorm[i];
    float uv0 = uv[vb], uv1 = uv[vb + FD], uv2 = uv[vb + 2 * FD];
    float vv0 = vv[vb], vv1 = vv[vb + FD], vv2 = vv[vb + 2 * FD];
    float gv0 = gv_in[vb], gv1 = gv_in[vb + FD], gv2 = gv_in[vb + 2 * FD];
    float guv0 = gv0 * avv + gS * vv0;
    float guv1 = gv1 * avv + gS * vv1;
    float guv2 = gv2 * avv + gS * vv2;
    float gvv0 = gS * uv0 + c * vv0;
    float gvv1 = gS * uv1 + c * vv1;
    float gvv2 = gS * uv2 + c * vv2;
    uv[vb] = guv0; uv[vb + FD] = guv1; uv[vb + 2 * FD] = guv2;
    vv[vb] = gvv0; vv[vb + FD] = gvv1; vv[vb + 2 * FD] = gvv2;
    gv_tmp[vb] = gv0; gv_tmp[vb + FD] = gv1; gv_tmp[vb + 2 * FD] = gv2;
    gx_mid[i] = gxv + g_cat[(size_t)n * 2 * FD + g];
}

// ---------------- message backward (per-src-atom aggregation) ----------------
// phi buffer is read (own atom only) then overwritten with g_phi; no __restrict__.
__global__ __launch_bounds__(128) void msg_bwd_kernel(
    const int* row_off_src, const int* perm_src, const int* dst_arr,
    const float* rbf_e, const float* drbf_e, const float* fcut_e, const float* dfc_e,
    const float* unit_e,
    const float* phi, const float* Wr, const float* br,
    const float* v_in,              // nullable (block 0)
    const float* gx_mid, const float* gv_mid,
    float* gphi_out,                // may alias phi
    float* gv_out,
    float* gd_e, float* gu_e)
{
    __shared__ float sWr[NBASE * FD3];
    __shared__ float sbr[FD3];
    __shared__ float red[8];
    int n = blockIdx.x, f = threadIdx.x;
    for (int i = f; i < NBASE * FD3; i += FD) sWr[i] = Wr[i];
    for (int i = f; i < FD3; i += FD) sbr[i] = br[i];
    __syncthreads();
    float ph0 = phi[(size_t)n * FD3 + f];
    float ph1 = phi[(size_t)n * FD3 + FD + f];
    float ph2 = phi[(size_t)n * FD3 + 2 * FD + f];
    float vs0 = 0.f, vs1 = 0.f, vs2 = 0.f;
    if (v_in) { const float* vp = v_in + (size_t)n * 3 * FD; vs0 = vp[f]; vs1 = vp[FD + f]; vs2 = vp[2 * FD + f]; }
    float gp0 = 0.f, gp1 = 0.f, gp2 = 0.f, ga0 = 0.f, ga1 = 0.f, ga2 = 0.f;
    int e0 = row_off_src[n], e1 = row_off_src[n + 1];
    for (int ii = e0; ii < e1; ++ii) {
        int e = perm_src[ii];
        int dd = dst_arr[e];
        float fc = fcut_e[e], dfc = dfc_e[e];
        float raw0 = sbr[f], raw1 = sbr[FD + f], raw2 = sbr[2 * FD + f];
        float A0 = 0.f, A1 = 0.f, A2 = 0.f;
        #pragma unroll
        for (int k = 0; k < NBASE; ++k) {
            float r = rbf_e[(size_t)e * NBASE + k];
            float dr = drbf_e[(size_t)e * NBASE + k];
            float w0 = sWr[k * FD3 + f], w1 = sWr[k * FD3 + FD + f], w2 = sWr[k * FD3 + 2 * FD + f];
            raw0 = fmaf(r, w0, raw0); raw1 = fmaf(r, w1, raw1); raw2 = fmaf(r, w2, raw2);
            A0 = fmaf(dr, w0, A0); A1 = fmaf(dr, w1, A1); A2 = fmaf(dr, w2, A2);
        }
        float f0 = raw0 * fc, f1 = raw1 * fc, f2 = raw2 * fc;
        float gds = gx_mid[(size_t)dd * FD + f];
        const float* gvp = gv_mid + (size_t)dd * 3 * FD;
        float gd0 = gvp[f], gd1 = gvp[FD + f], gd2 = gvp[2 * FD + f];
        float u0 = unit_e[e * 3], u1 = unit_e[e * 3 + 1], u2 = unit_e[e * 3 + 2];
        float dv1 = ph1 * f1, dv2 = ph2 * f2;
        float gdv1 = gd0 * vs0 + gd1 * vs1 + gd2 * vs2;
        float gdv2 = gd0 * u0 + gd1 * u1 + gd2 * u2;
        ga0 += gd0 * dv1; ga1 += gd1 * dv1; ga2 += gd2 * dv1;
        gp0 += gds * f0; gp1 += gdv1 * f1; gp2 += gdv2 * f2;
        float gf0 = gds * ph0, gf1 = gdv1 * ph1, gf2 = gdv2 * ph2;
        float pd = fc * (gf0 * A0 + gf1 * A1 + gf2 * A2)
                 + dfc * (gf0 * raw0 + gf1 * raw1 + gf2 * raw2);
        float r0 = pd, r1 = gd0 * dv2, r2 = gd1 * dv2, r3 = gd2 * dv2;
        #pragma unroll
        for (int off = 32; off > 0; off >>= 1) {
            r0 += __shfl_down(r0, off);
            r1 += __shfl_down(r1, off);
            r2 += __shfl_down(r2, off);
            r3 += __shfl_down(r3, off);
        }
        int lane = f & 63, wv = f >> 6;
        if (lane == 0) { red[wv * 4] = r0; red[wv * 4 + 1] = r1; red[wv * 4 + 2] = r2; red[wv * 4 + 3] = r3; }
        __syncthreads();
        if (f == 0) {
            gd_e[e] += red[0] + red[4];
            gu_e[e * 3]     += red[1] + red[5];
            gu_e[e * 3 + 1] += red[2] + red[6];
            gu_e[e * 3 + 2] += red[3] + red[7];
        }
        __syncthreads();
    }
    gphi_out[(size_t)n * FD3 + f] = gp0;
    gphi_out[(size_t)n * FD3 + FD + f] = gp1;
    gphi_out[(size_t)n * FD3 + 2 * FD + f] = gp2;
    size_t vb = (size_t)n * 3 * FD + f;
    gv_out[vb] = gv_mid[vb] + ga0;
    gv_out[vb + FD] = gv_mid[vb + FD] + ga1;
    gv_out[vb + 2 * FD] = gv_mid[vb + 2 * FD] + ga2;
}

// ---------------- geometry backward → coordinate gradient ----------------
__global__ void geom_bwd_kernel(const float* coord, const int* ei,
    const float* d_e, const float* gd_e, const float* gu_e, float* gcoord)
{
    int e = blockIdx.x * blockDim.x + threadIdx.x;
    if (e >= NE) return;
    int s = ei[e], t = ei[NE + e];
    float rx = coord[t * 3 + 0] - coord[s * 3 + 0];
    float ry = coord[t * 3 + 1] - coord[s * 3 + 1];
    float rz = coord[t * 3 + 2] - coord[s * 3 + 2];
    float dd = d_e[e];
    float inv = 1.f / dd;
    float gu0 = gu_e[e * 3], gu1 = gu_e[e * 3 + 1], gu2 = gu_e[e * 3 + 2];
    float gd = gd_e[e];
    float dot = gu0 * rx + gu1 * ry + gu2 * rz;
    float coef = gd * inv - dot * inv * inv * inv;
    float gx = gu0 * inv + coef * rx;
    float gy = gu1 * inv + coef * ry;
    float gz = gu2 * inv + coef * rz;
    atomicAdd(&gcoord[t * 3 + 0], gx);  atomicAdd(&gcoord[t * 3 + 1], gy);  atomicAdd(&gcoord[t * 3 + 2], gz);
    atomicAdd(&gcoord[s * 3 + 0], -gx); atomicAdd(&gcoord[s * 3 + 1], -gy); atomicAdd(&gcoord[s * 3 + 2], -gz);
}

// ======================================================================
extern "C" void kernel_launch(void* const* d_in, const int* in_sizes, int n_in,
                              void* d_out, int out_size, void* d_ws, size_t ws_size,
                              hipStream_t stream)
{
    (void)in_sizes; (void)n_in; (void)out_size; (void)ws_size;
    const int*   at_no   = (const int*)  d_in[0];
    const float* coord   = (const float*)d_in[1];
    const int*   eidx    = (const int*)  d_in[2];
    const float* emb     = (const float*)d_in[5];
    const float* atom_sp = (const float*)d_in[6];
    const float* msg_w1  = (const float*)d_in[7];
    const float* msg_b1  = (const float*)d_in[8];
    const float* msg_w2  = (const float*)d_in[9];
    const float* msg_b2  = (const float*)d_in[10];
    const float* msg_wr  = (const float*)d_in[11];
    const float* msg_br  = (const float*)d_in[12];
    const float* upd_u   = (const float*)d_in[13];
    const float* upd_v   = (const float*)d_in[14];
    const float* upd_w1  = (const float*)d_in[15];
    const float* upd_b1  = (const float*)d_in[16];
    const float* upd_w2  = (const float*)d_in[17];
    const float* upd_b2  = (const float*)d_in[18];
    const float* out_w1  = (const float*)d_in[19];
    const float* out_b1  = (const float*)d_in[20];
    const float* out_w2  = (const float*)d_in[21];
    const float* out_b2  = (const float*)d_in[22];
    float* out = (float*)d_out;
    float* gcoord = out + 1;

    char* wp = (char*)d_ws;
    auto alloc = [&](size_t nelem) -> float* {
        float* r = (float*)wp; wp += ((nelem * 4 + 255) & ~(size_t)255); return r;
    };
    auto alloci = [&](size_t nelem) -> int* {
        int* r = (int*)wp; wp += ((nelem * 4 + 255) & ~(size_t)255); return r;
    };
    const size_t NF = (size_t)NA * FD;

    float* d_e    = alloc(NE);
    float* unit_e = alloc(3 * (size_t)NE);
    float* rbf_e  = alloc((size_t)NBASE * NE);
    float* drbf_e = alloc((size_t)NBASE * NE);
    float* fcut_e = alloc(NE);
    float* dfc_e  = alloc(NE);
    float* gd_e   = alloc(NE);
    float* gu_e   = alloc(3 * (size_t)NE);
    int* cnt_dst = alloci(NA); int* cnt_src = alloci(NA);
    int* off_dst = alloci(NA + 1); int* off_src = alloci(NA + 1);
    int* cur_dst = alloci(NA); int* cur_src = alloci(NA);
    int* perm_dst = alloci(NE); int* perm_src = alloci(NE);
    float* xin0 = alloc(NF); float* xin1 = alloc(NF); float* xfin = alloc(NF);
    float* vout0 = alloc(3 * NF);
    float* xmid = alloc(NF);
    float* vmid = alloc(3 * NF);            // reused as gv_tmp in backward
    float* catb = alloc(2 * NF);
    float* toutb = alloc((size_t)NA * HD);
    float *s1b[2], *phib[2], *uvb[2], *vvb[2], *vnb[2], *t1b[2], *ab[2];
    for (int b = 0; b < 2; ++b) {
        s1b[b] = alloc(NF); phib[b] = alloc(3 * NF); uvb[b] = alloc(3 * NF); vvb[b] = alloc(3 * NF);
        vnb[b] = alloc(NF); t1b[b] = alloc(NF); ab[b] = alloc(3 * NF);
    }
    float* gxA = alloc(NF); float* gxB = alloc(NF);
    float* gvA = alloc(3 * NF);
    float* g_a = alloc(3 * NF);
    float* g_t1 = alloc(NF);
    float* g_cat = alloc(2 * NF);
    float* g_s1 = alloc(NF);
    float *mw1T[2], *mw2T[2], *uw1T[2], *uw2T[2], *uT[2], *vT[2];
    for (int b = 0; b < 2; ++b) {
        mw1T[b] = alloc(FD * FD); mw2T[b] = alloc(FD * FD3); uw1T[b] = alloc(2 * FD * FD);
        uw2T[b] = alloc(FD * FD3); uT[b] = alloc(FD * FD); vT[b] = alloc(FD * FD);
    }

    // zero-init (harness poisons d_out/d_ws with 0xAA before every call)
    hipMemsetAsync(d_out, 0, (size_t)(1 + NA * 3) * 4, stream);
    hipMemsetAsync(cnt_dst, 0, (size_t)NA * 4, stream);
    hipMemsetAsync(cnt_src, 0, (size_t)NA * 4, stream);
    hipMemsetAsync(gd_e, 0, (size_t)NE * 4, stream);
    hipMemsetAsync(gu_e, 0, 3ull * NE * 4, stream);
    hipMemsetAsync(gvA, 0, 3 * NF * 4, stream);

    geom_fwd_kernel<<<NE / 256, 256, 0, stream>>>(coord, eidx, d_e, unit_e, rbf_e, drbf_e, fcut_e, dfc_e);
    hist_kernel<<<NE / 256, 256, 0, stream>>>(eidx, cnt_dst, cnt_src);
    scan_kernel<<<2, 1024, 0, stream>>>(cnt_dst, cnt_src, off_dst, off_src, cur_dst, cur_src);
    scatter_kernel<<<NE / 256, 256, 0, stream>>>(eidx, cur_dst, cur_src, perm_dst, perm_src);
    embed_kernel<<<NF / 256, 256, 0, stream>>>(at_no, emb, xin0);

    auto transpose = [&](const float* inp, float* outp, int R, int C) {
        transpose_kernel<<<(R * C + 255) / 256, 256, 0, stream>>>(inp, outp, R, C);
    };
    for (int b = 0; b < 2; ++b) {
        transpose(msg_w1 + (size_t)b * FD * FD,   mw1T[b], FD, FD);
        transpose(msg_w2 + (size_t)b * FD * FD3,  mw2T[b], FD, FD3);
        transpose(upd_w1 + (size_t)b * 2 * FD * FD, uw1T[b], 2 * FD, FD);
        transpose(upd_w2 + (size_t)b * FD * FD3,  uw2T[b], FD, FD3);
        transpose(upd_u + (size_t)b * FD * FD,    uT[b], FD, FD);
        transpose(upd_v + (size_t)b * FD * FD,    vT[b], FD, FD);
    }

    auto gemm = [&](const float* A, const float* W, const float* bias, const float* dsil,
                    const float* addb, float* C, int M, int Nn, int K, int asilu, int acc) {
        dim3 g(Nn / 64, M / 64);
        gemm_kernel<<<g, 256, 0, stream>>>(A, W, bias, dsil, addb, C, M, Nn, K, asilu, acc);
    };

    // ---------------- forward ----------------
    for (int b = 0; b < 2; ++b) {
        const float* xinb = b ? xin1 : xin0;
        const float* vin  = b ? vout0 : nullptr;
        gemm(xinb, msg_w1 + (size_t)b * FD * FD, msg_b1 + b * FD, nullptr, nullptr, s1b[b], NA, FD, FD, 0, 0);
        gemm(s1b[b], msg_w2 + (size_t)b * FD * FD3, msg_b2 + b * FD3, nullptr, nullptr, phib[b], NA, FD3, FD, 1, 0);
        msg_fwd_kernel<<<NA, FD, 0, stream>>>(off_dst, perm_dst, eidx, rbf_e, fcut_e, unit_e,
                                              phib[b], msg_wr + (size_t)b * NBASE * FD3, msg_br + b * FD3,
                                              xinb, vin, xmid, vmid);
        gemm(vmid, upd_u + (size_t)b * FD * FD, nullptr, nullptr, nullptr, uvb[b], 3 * NA, FD, FD, 0, 0);
        gemm(vmid, upd_v + (size_t)b * FD * FD, nullptr, nullptr, nullptr, vvb[b], 3 * NA, FD, FD, 0, 0);
        vnorm_cat_kernel<<<NF / 256, 256, 0, stream>>>(xmid, vvb[b], vnb[b], catb);
        gemm(catb, upd_w1 + (size_t)b * 2 * FD * FD, upd_b1 + b * FD, nullptr, nullptr, t1b[b], NA, FD, 2 * FD, 0, 0);
        gemm(t1b[b], upd_w2 + (size_t)b * FD * FD3, upd_b2 + b * FD3, nullptr, nullptr, ab[b], NA, FD3, FD, 1, 0);
        combine_kernel<<<NF / 256, 256, 0, stream>>>(xmid, vmid, uvb[b], vvb[b], ab[b],
                                                     b ? xfin : xin1, b ? nullptr : vout0);
    }
    gemm(xfin, out_w1, out_b1, nullptr, nullptr, toutb, NA, HD, FD, 0, 0);
    energy_kernel<<<NA / 256, 256, 0, stream>>>(toutb, out_w2, out_b2, atom_sp, at_no, out);

    // ---------------- backward ----------------
    head_bwd_kernel<<<NA, FD, 0, stream>>>(toutb, out_w1, out_w2, gxA);
    for (int b = 1; b >= 0; --b) {
        ubwd1_kernel<<<NF / 256, 256, 0, stream>>>(gxA, gvA, uvb[b], vvb[b], g_a);
        gemm(g_a, uw2T[b], nullptr, t1b[b], nullptr, g_t1, NA, FD, FD3, 0, 0);
        gemm(g_t1, uw1T[b], nullptr, nullptr, nullptr, g_cat, NA, 2 * FD, FD, 0, 0);
        ubwd2_kernel<<<NF / 256, 256, 0, stream>>>(gxA, gvA, ab[b], vnb[b], g_cat,
                                                   uvb[b], vvb[b], gxB, vmid);
        gemm(uvb[b], uT[b], nullptr, nullptr, nullptr, vmid, 3 * NA, FD, FD, 0, 1);
        gemm(vvb[b], vT[b], nullptr, nullptr, nullptr, vmid, 3 * NA, FD, FD, 0, 1);
        msg_bwd_kernel<<<NA, FD, 0, stream>>>(off_src, perm_src, eidx + NE,
                                              rbf_e, drbf_e, fcut_e, dfc_e, unit_e,
                                              phib[b], msg_wr + (size_t)b * NBASE * FD3, msg_br + b * FD3,
                                              b ? vout0 : nullptr, gxB, vmid,
                                              phib[b], gvA, gd_e, gu_e);
        if (b == 1) {
            gemm(phib[b], mw2T[b], nullptr, s1b[b], nullptr, g_s1, NA, FD, FD3, 0, 0);
            gemm(g_s1, mw1T[b], nullptr, nullptr, gxB, gxA, NA, FD, FD, 0, 0);
        }
    }
    geom_bwd_kernel<<<NE / 256, 256, 0, stream>>>(coord, eidx, d_e, gd_e, gu_e, gcoord);
}